// Round 7
// baseline (4748.725 us; speedup 1.0000x reference)
//
#include <hip/hip_runtime.h>

#define TLEN 2048
#define BATCH 32
#define DIN 64
#define HID 128

typedef _Float16 h2 __attribute__((ext_vector_type(2)));
typedef float f4 __attribute__((ext_vector_type(4)));
typedef unsigned int u32;

#if defined(__has_builtin)
#if __has_builtin(__builtin_amdgcn_fdot2)
#define FDOT2(a, b, c) __builtin_amdgcn_fdot2((a), (b), (c), false)
#endif
#endif
#ifndef FDOT2
#define FDOT2(a, b, c) ((c) + (float)(a).x * (float)(b).x + (float)(a).y * (float)(b).y)
#endif

#define DOT2U(wu, hv, acc) FDOT2(__builtin_bit_cast(h2, (wu)), (hv), (acc))

__device__ __forceinline__ float sigm(float x) { return 1.0f / (1.0f + __expf(-x)); }
__device__ __forceinline__ float tanh_c(float x) {
    x = fminf(fmaxf(x, -15.0f), 15.0f);
    float e = __expf(2.0f * x);
    return (e - 1.0f) / (e + 1.0f);
}

// quad butterfly (R1/R3/R5-proven __shfl_xor idiom, width 4)
__device__ __forceinline__ void qreduce(float (&v)[4]) {
    #pragma unroll
    for (int m = 0; m < 4; ++m) {
        v[m] += __shfl_xor(v[m], 1, 4);
        v[m] += __shfl_xor(v[m], 2, 4);
    }
}

// ============================================================================
// Kernel 1: XG[b,t,j] = Wih0[row_j]·x[b,t] + bih0[row_j] + bhh0[row_j],
// row_j = (j>>2) + 128*(j&3)  (unit j>>2, gate j&3); coalesced stores.
// ============================================================================
template <typename XT>
__global__ __launch_bounds__(512) void xg_precompute(
    const float* __restrict__ X, const float* __restrict__ Wih0,
    const float* __restrict__ bih0, const float* __restrict__ bhh0,
    XT* __restrict__ XG)
{
    __shared__ float xs[16][DIN];
    const int blk = blockIdx.x;               // over B * (T/16)
    const int b   = blk / (TLEN / 16);
    const int tc  = blk % (TLEN / 16);
    const int j   = threadIdx.x;
    const int row = (j >> 2) + 128 * (j & 3);

    const float* xsrc = X + ((size_t)b * TLEN + (size_t)tc * 16) * DIN;
    for (int i = j; i < 16 * DIN; i += 512) ((float*)xs)[i] = xsrc[i];
    __syncthreads();

    f4 w[16];
    const f4* wp = (const f4*)(Wih0 + (size_t)row * DIN);
    #pragma unroll
    for (int i = 0; i < 16; ++i) w[i] = wp[i];
    const float bias = bih0[row] + bhh0[row];

    XT* dst = XG + ((size_t)b * TLEN + (size_t)tc * 16) * 512 + j;
    #pragma unroll 4
    for (int t = 0; t < 16; ++t) {
        float acc = bias;
        const f4* xv = (const f4*)&xs[t][0];
        #pragma unroll
        for (int i = 0; i < 16; ++i) {
            f4 x4 = xv[i];
            acc += w[i][0] * x4[0] + w[i][1] * x4[1] + w[i][2] * x4[2] + w[i][3] * x4[3];
        }
        dst[(size_t)t * 512] = (XT)acc;
    }
}

// ============================================================================
// Kernel 2: persistent fused 2-layer LSTM, one block per batch element.
// Thread t0: unit rg = t0>>2, k-slice kg = t0&3 (32 h-elements each).
//
// Register strategy (R3/R5/R6 evidence: arch-VGPR alloc is HARD-CAPPED at
// 128 regardless of launch_bounds / waves_per_eu):
//   - wih1+whh1 (128 dwords, the q-path) -> AGPR file via "+a" pins.
//     gfx950 unified file: 128 arch + 128 acc = 256/wave, launchable at
//     2 waves/SIMD for an 8-wave block. CDNA2+ VALU can source AGPRs
//     (worst case compiler inserts v_accvgpr_read per use).
//   - whh0 (64 dwords, p-path) stays "+v"-pinned in arch: 64 + ~60 working
//     ~= 124 <= 128 cap, no scratch churn.
//   - pins re-asserted each iteration so the allocator cannot split the
//     live range back into the (full) arch file.
//
// Iter tt: layer0 -> h0(tt+1) from xg(tt+1), h0(tt);
//          layer1 -> h1(tt)   from h0(tt),  h1(tt-1).   ONE barrier/step.
// ============================================================================
template <typename XT>
__global__ __attribute__((amdgpu_flat_work_group_size(512, 512),
                          amdgpu_waves_per_eu(2, 2)))
void lstm2_fused(
    const XT* __restrict__ XG,
    const float* __restrict__ Whh0,
    const float* __restrict__ Wih1, const float* __restrict__ Whh1,
    const float* __restrict__ bih1, const float* __restrict__ bhh1,
    float* __restrict__ Out)
{
    __shared__ alignas(16) _Float16 h0buf[2][HID];
    __shared__ alignas(16) _Float16 h1buf[2][HID];

    const int b  = blockIdx.x;
    const int t0 = threadIdx.x;
    const int rg = t0 >> 2;
    const int kg = t0 & 3;

    // ---- weights -> registers as raw u32 (f16 pairs) ----
    u32 whh0u[4][16], wih1u[4][16], whh1u[4][16];
    #pragma unroll
    for (int m = 0; m < 4; ++m) {
        const int row = rg + 128 * m;
        const float2* a = (const float2*)(Whh0 + (size_t)row * HID + kg * 32);
        const float2* c = (const float2*)(Wih1 + (size_t)row * HID + kg * 32);
        const float2* d = (const float2*)(Whh1 + (size_t)row * HID + kg * 32);
        #pragma unroll
        for (int i = 0; i < 16; ++i) {
            float2 v; h2 w;
            v = a[i]; w.x = (_Float16)v.x; w.y = (_Float16)v.y;
            whh0u[m][i] = __builtin_bit_cast(u32, w);
            v = c[i]; w.x = (_Float16)v.x; w.y = (_Float16)v.y;
            wih1u[m][i] = __builtin_bit_cast(u32, w);
            v = d[i]; w.x = (_Float16)v.x; w.y = (_Float16)v.y;
            whh1u[m][i] = __builtin_bit_cast(u32, w);
        }
    }
    // initial placement pins: p-path -> arch VGPR, q-path -> AGPR
    #pragma unroll
    for (int m = 0; m < 4; ++m) {
        #pragma unroll
        for (int i = 0; i < 16; ++i) {
            asm volatile("" : "+v"(whh0u[m][i]));
            asm volatile("" : "+a"(wih1u[m][i]));
            asm volatile("" : "+a"(whh1u[m][i]));
        }
    }

    // layer-1 bias for the gate this lane injects (gate index == kg)
    const float B1 = bih1[rg + 128 * kg] + bhh1[rg + 128 * kg];

    if (t0 < HID) {
        h0buf[0][t0] = (_Float16)0.0f; h0buf[1][t0] = (_Float16)0.0f;
        h1buf[0][t0] = (_Float16)0.0f; h1buf[1][t0] = (_Float16)0.0f;
    }
    __syncthreads();

    const XT* xgp = XG + ((size_t)b * TLEN) * 512 + t0;
    float c0 = 0.0f, c1 = 0.0f;

    // prologue: h0(0) from xg(0), h0(-1)=0
    {
        float xg0 = (float)xgp[0];
        float p[4];
        #pragma unroll
        for (int m = 0; m < 4; ++m) p[m] = (kg == m) ? xg0 : 0.0f;
        qreduce(p);
        float ii = sigm(p[0]), gg = tanh_c(p[2]), oo = sigm(p[3]);
        c0 = ii * gg;
        if (kg == 0) h0buf[0][rg] = (_Float16)(oo * tanh_c(c0));
    }
    __syncthreads();

    // xg prefetch ring (depth 2)
    float xg_next = (float)xgp[512];          // xg(1), used at iter 0
    XT    xg_pend = xgp[2 * 512];             // xg(2), used at iter 1

    for (int tt = 0; tt < TLEN; ++tt) {
        const int cur = tt & 1, nxt = cur ^ 1;

        // re-assert register-file placement each iteration (zero-cost asm):
        // blocks live-range splitting / remat back into the capped arch file
        #pragma unroll
        for (int m = 0; m < 4; ++m) {
            #pragma unroll
            for (int i = 0; i < 16; ++i) {
                asm volatile("" : "+v"(whh0u[m][i]));
                asm volatile("" : "+a"(wih1u[m][i]));
                asm volatile("" : "+a"(whh1u[m][i]));
            }
        }

        const float xgn = xg_next;            // xg(tt+1)
        xg_next = (float)xg_pend;
        {
            const int tnn = (tt + 3 < TLEN) ? tt + 3 : TLEN - 1;
            xg_pend = xgp[(size_t)tnn * 512];
        }

        float p[4], q[4];
        #pragma unroll
        for (int m = 0; m < 4; ++m) {
            p[m] = (kg == m) ? xgn : 0.0f;
            q[m] = (kg == m) ? B1  : 0.0f;
        }

        // this lane's 32-element slices of h0(tt) and h1(tt-1): 4 b128 each,
        // broadcast addresses (4 distinct per wave) -> conflict-free
        const uint4* H0 = (const uint4*)&h0buf[cur][kg * 32];
        const uint4* H1 = (const uint4*)&h1buf[cur][kg * 32];
        #pragma unroll
        for (int qr = 0; qr < 4; ++qr) {
            u32 hw[4], gw[4];
            *(uint4*)&hw[0] = H0[qr];
            *(uint4*)&gw[0] = H1[qr];
            #pragma unroll
            for (int w = 0; w < 4; ++w) {
                const int i = qr * 4 + w;    // pair index 0..15
                const h2 hv = __builtin_bit_cast(h2, hw[w]);
                const h2 gv = __builtin_bit_cast(h2, gw[w]);
                #pragma unroll
                for (int m = 0; m < 4; ++m) {
                    p[m] = DOT2U(whh0u[m][i], hv, p[m]);
                    q[m] = DOT2U(wih1u[m][i], hv, q[m]);
                    q[m] = DOT2U(whh1u[m][i], gv, q[m]);
                }
            }
        }

        qreduce(p);
        qreduce(q);

        // layer0 -> h0(tt+1)
        {
            float ii = sigm(p[0]), ff = sigm(p[1]);
            float gg = tanh_c(p[2]), oo = sigm(p[3]);
            c0 = ff * c0 + ii * gg;
            if (kg == 0) h0buf[nxt][rg] = (_Float16)(oo * tanh_c(c0));
        }
        // layer1 -> h1(tt)
        {
            float ii = sigm(q[0]), ff = sigm(q[1]);
            float gg = tanh_c(q[2]), oo = sigm(q[3]);
            c1 = ff * c1 + ii * gg;
            float h1v = oo * tanh_c(c1);
            if (kg == 0) {
                h1buf[nxt][rg] = (_Float16)h1v;
                Out[((size_t)b * TLEN + tt) * HID + rg] = h1v;
            }
        }
        __syncthreads();
    }
}

// ============================================================================
// Fallback (ws too small): round-1 kernel, known-correct at 6.8 ms.
// ============================================================================
__global__ __launch_bounds__(512, 2) void lstm2_persist(
    const float* __restrict__ X,
    const float* __restrict__ Wih0, const float* __restrict__ Whh0,
    const float* __restrict__ bih0, const float* __restrict__ bhh0,
    const float* __restrict__ Wih1, const float* __restrict__ Whh1,
    const float* __restrict__ bih1, const float* __restrict__ bhh1,
    float* __restrict__ Out)
{
    __shared__ unsigned int wih0_lds[512 * 33];
    __shared__ _Float16 h0buf[2][HID];
    __shared__ _Float16 h1buf[2][HID];

    const int b  = blockIdx.x;
    const int t  = threadIdx.x;
    const int rg = t >> 2;
    const int kg = t & 3;

    {
        const float2* src = (const float2*)(Wih0 + t * DIN);
        #pragma unroll
        for (int i = 0; i < 32; ++i) {
            float2 v = src[i];
            h2 p; p.x = (_Float16)v.x; p.y = (_Float16)v.y;
            wih0_lds[t * 33 + i] = __builtin_bit_cast(unsigned int, p);
        }
    }
    if (t < HID) {
        h0buf[0][t] = (_Float16)0.0f; h0buf[1][t] = (_Float16)0.0f;
        h1buf[0][t] = (_Float16)0.0f; h1buf[1][t] = (_Float16)0.0f;
    }

    h2 whh0[4][16], wih1[4][16], whh1[4][16];
    float bi0[4], bi1[4];
    #pragma unroll
    for (int m = 0; m < 4; ++m) {
        const int row = rg + 128 * m;
        const float2* a = (const float2*)(Whh0 + row * HID + kg * 32);
        const float2* c = (const float2*)(Wih1 + row * HID + kg * 32);
        const float2* d = (const float2*)(Whh1 + row * HID + kg * 32);
        #pragma unroll
        for (int i = 0; i < 16; ++i) {
            float2 v; h2 w;
            v = a[i]; w.x = (_Float16)v.x; w.y = (_Float16)v.y; whh0[m][i] = w;
            v = c[i]; w.x = (_Float16)v.x; w.y = (_Float16)v.y; wih1[m][i] = w;
            v = d[i]; w.x = (_Float16)v.x; w.y = (_Float16)v.y; whh1[m][i] = w;
        }
        bi0[m] = (kg == 0) ? (bih0[row] + bhh0[row]) : 0.0f;
        bi1[m] = (kg == 0) ? (bih1[row] + bhh1[row]) : 0.0f;
    }

    float c0 = 0.0f, c1 = 0.0f;
    __syncthreads();

    f4 xA[4], xB[4];
    {
        const f4* xp = (const f4*)(X + ((size_t)b * TLEN) * DIN + kg * 16);
        #pragma unroll
        for (int j = 0; j < 4; ++j) xA[j] = xp[j];
    }

    auto step = [&](int tt, f4 (&xc)[4], f4 (&xn)[4]) {
        const int cur = tt & 1, nxt = cur ^ 1;
        h2 xh[8];
        const float* xf = (const float*)xc;
        #pragma unroll
        for (int j = 0; j < 8; ++j) {
            h2 p; p.x = (_Float16)xf[2 * j]; p.y = (_Float16)xf[2 * j + 1];
            xh[j] = p;
        }
        {
            const int tn = (tt + 1 < TLEN) ? tt + 1 : TLEN - 1;
            const f4* xp = (const f4*)(X + ((size_t)b * TLEN + tn) * DIN + kg * 16);
            #pragma unroll
            for (int j = 0; j < 4; ++j) xn[j] = xp[j];
        }
        float p0[4];
        #pragma unroll
        for (int m = 0; m < 4; ++m) p0[m] = bi0[m];
        #pragma unroll
        for (int m = 0; m < 4; ++m) {
            const unsigned int* wr = &wih0_lds[(rg + 128 * m) * 33 + kg * 8];
            #pragma unroll
            for (int i = 0; i < 8; ++i) {
                h2 w = __builtin_bit_cast(h2, wr[i]);
                p0[m] = FDOT2(w, xh[i], p0[m]);
            }
        }
        {
            const unsigned int* hr = (const unsigned int*)&h0buf[cur][0];
            #pragma unroll
            for (int i = 0; i < 16; ++i) {
                h2 hv = __builtin_bit_cast(h2, hr[kg * 16 + i]);
                #pragma unroll
                for (int m = 0; m < 4; ++m)
                    p0[m] = FDOT2(whh0[m][i], hv, p0[m]);
            }
        }
        #pragma unroll
        for (int m = 0; m < 4; ++m) {
            p0[m] += __shfl_xor(p0[m], 1, 4);
            p0[m] += __shfl_xor(p0[m], 2, 4);
        }
        {
            float ii = sigm(p0[0]), ff = sigm(p0[1]);
            float gg = tanh_c(p0[2]), oo = sigm(p0[3]);
            c0 = ff * c0 + ii * gg;
            float h0v = oo * tanh_c(c0);
            if (kg == 0) h0buf[nxt][rg] = (_Float16)h0v;
        }
        __syncthreads();
        float q[4];
        #pragma unroll
        for (int m = 0; m < 4; ++m) q[m] = bi1[m];
        {
            const unsigned int* hr = (const unsigned int*)&h0buf[nxt][0];
            #pragma unroll
            for (int i = 0; i < 16; ++i) {
                h2 hv = __builtin_bit_cast(h2, hr[kg * 16 + i]);
                #pragma unroll
                for (int m = 0; m < 4; ++m)
                    q[m] = FDOT2(wih1[m][i], hv, q[m]);
            }
        }
        {
            const unsigned int* hr = (const unsigned int*)&h1buf[cur][0];
            #pragma unroll
            for (int i = 0; i < 16; ++i) {
                h2 hv = __builtin_bit_cast(h2, hr[kg * 16 + i]);
                #pragma unroll
                for (int m = 0; m < 4; ++m)
                    q[m] = FDOT2(whh1[m][i], hv, q[m]);
            }
        }
        #pragma unroll
        for (int m = 0; m < 4; ++m) {
            q[m] += __shfl_xor(q[m], 1, 4);
            q[m] += __shfl_xor(q[m], 2, 4);
        }
        {
            float ii = sigm(q[0]), ff = sigm(q[1]);
            float gg = tanh_c(q[2]), oo = sigm(q[3]);
            c1 = ff * c1 + ii * gg;
            float h1v = oo * tanh_c(c1);
            if (kg == 0) {
                h1buf[nxt][rg] = (_Float16)h1v;
                Out[((size_t)b * TLEN + tt) * HID + rg] = h1v;
            }
        }
        __syncthreads();
    };

    for (int tt = 0; tt < TLEN; tt += 2) {
        step(tt, xA, xB);
        step(tt + 1, xB, xA);
    }
}

extern "C" void kernel_launch(void* const* d_in, const int* in_sizes, int n_in,
                              void* d_out, int out_size, void* d_ws, size_t ws_size,
                              hipStream_t stream) {
    const float* X    = (const float*)d_in[0];
    const float* Wih0 = (const float*)d_in[1];
    const float* Whh0 = (const float*)d_in[2];
    const float* bih0 = (const float*)d_in[3];
    const float* bhh0 = (const float*)d_in[4];
    const float* Wih1 = (const float*)d_in[5];
    const float* Whh1 = (const float*)d_in[6];
    const float* bih1 = (const float*)d_in[7];
    const float* bhh1 = (const float*)d_in[8];
    float* Out = (float*)d_out;

    const size_t NG = (size_t)BATCH * TLEN * 512;        // xg element count
    if (ws_size >= NG * sizeof(float)) {
        float* XG = (float*)d_ws;
        xg_precompute<float><<<dim3(BATCH * (TLEN / 16)), dim3(512), 0, stream>>>(
            X, Wih0, bih0, bhh0, XG);
        lstm2_fused<float><<<dim3(BATCH), dim3(512), 0, stream>>>(
            XG, Whh0, Wih1, Whh1, bih1, bhh1, Out);
    } else if (ws_size >= NG * sizeof(_Float16)) {
        _Float16* XG = (_Float16*)d_ws;
        xg_precompute<_Float16><<<dim3(BATCH * (TLEN / 16)), dim3(512), 0, stream>>>(
            X, Wih0, bih0, bhh0, XG);
        lstm2_fused<_Float16><<<dim3(BATCH), dim3(512), 0, stream>>>(
            XG, Whh0, Wih1, Whh1, bih1, bhh1, Out);
    } else {
        lstm2_persist<<<dim3(BATCH), dim3(512), 0, stream>>>(
            X, Wih0, Whh0, bih0, bhh0, Wih1, Whh1, bih1, bhh1, Out);
    }
}

// Round 8
// 2548.852 us; speedup vs baseline: 1.8631x; 1.8631x over previous
//
#include <hip/hip_runtime.h>

#define TLEN 2048
#define BATCH 32
#define DIN 64
#define HID 128
#define RING 256   // xg1 ring depth (steps); power of 2

typedef _Float16 h2 __attribute__((ext_vector_type(2)));
typedef float f4 __attribute__((ext_vector_type(4)));
typedef unsigned int u32;

#if defined(__has_builtin)
#if __has_builtin(__builtin_amdgcn_fdot2)
#define FDOT2(a, b, c) __builtin_amdgcn_fdot2((a), (b), (c), false)
#endif
#endif
#ifndef FDOT2
#define FDOT2(a, b, c) ((c) + (float)(a).x * (float)(b).x + (float)(a).y * (float)(b).y)
#endif
#define DOT2U(wu, hv, acc) FDOT2(__builtin_bit_cast(h2, (wu)), (hv), (acc))

__device__ __forceinline__ float sigm(float x) { return 1.0f / (1.0f + __expf(-x)); }
__device__ __forceinline__ float tanh_c(float x) {
    x = fminf(fmaxf(x, -15.0f), 15.0f);
    float e = __expf(2.0f * x);
    return (e - 1.0f) / (e + 1.0f);
}
__device__ __forceinline__ void qreduce(float (&v)[4]) {
    #pragma unroll
    for (int m = 0; m < 4; ++m) {
        v[m] += __shfl_xor(v[m], 1, 4);
        v[m] += __shfl_xor(v[m], 2, 4);
    }
}

// agent-scope atomics: the documented cross-XCD-coherent path
__device__ __forceinline__ u32 aload_rlx(u32* p) {
    return __hip_atomic_load(p, __ATOMIC_RELAXED, __HIP_MEMORY_SCOPE_AGENT);
}
__device__ __forceinline__ u32 aload_acq(u32* p) {
    return __hip_atomic_load(p, __ATOMIC_ACQUIRE, __HIP_MEMORY_SCOPE_AGENT);
}
__device__ __forceinline__ void astore_rlx(u32* p, u32 v) {
    __hip_atomic_store(p, v, __ATOMIC_RELAXED, __HIP_MEMORY_SCOPE_AGENT);
}
__device__ __forceinline__ void astore_rel(u32* p, u32 v) {
    __hip_atomic_store(p, v, __ATOMIC_RELEASE, __HIP_MEMORY_SCOPE_AGENT);
}

// f16-pair weight slice for gate rows {rg+128m}, k-slice [kg*32, kg*32+32)
__device__ __forceinline__ void load_w_slice(const float* __restrict__ W,
                                             int rg, int kg, u32 (&w)[64]) {
    #pragma unroll
    for (int m = 0; m < 4; ++m) {
        const float2* a = (const float2*)(W + (size_t)(rg + 128 * m) * HID + kg * 32);
        #pragma unroll
        for (int i = 0; i < 16; ++i) {
            float2 v = a[i];
            h2 x; x.x = (_Float16)v.x; x.y = (_Float16)v.y;
            w[m * 16 + i] = __builtin_bit_cast(u32, x);
        }
    }
}
// 64 dot2 over a 32-elem f16 h-slice (LDS), accumulating 4 gate partials
__device__ __forceinline__ void dot_slice(const u32 (&w)[64],
                                          const uint4* __restrict__ H,
                                          float (&p)[4]) {
    #pragma unroll
    for (int qr = 0; qr < 4; ++qr) {
        u32 hw[4];
        *(uint4*)hw = H[qr];
        #pragma unroll
        for (int ww = 0; ww < 4; ++ww) {
            const h2 hv = __builtin_bit_cast(h2, hw[ww]);
            #pragma unroll
            for (int m = 0; m < 4; ++m)
                p[m] = DOT2U(w[m * 16 + qr * 4 + ww], hv, p[m]);
        }
    }
}

// ============================================================================
// Kernel 1: XG0[b,t,j] = Wih0[row_j]·x[b,t] + bih0[row_j] + bhh0[row_j], f16.
// row_j = (j>>2) + 128*(j&3); layout matches pipeline thread mapping.
// ============================================================================
__global__ __launch_bounds__(512) void xg_precompute(
    const float* __restrict__ X, const float* __restrict__ Wih0,
    const float* __restrict__ bih0, const float* __restrict__ bhh0,
    _Float16* __restrict__ XG)
{
    __shared__ float xs[16][DIN];
    const int blk = blockIdx.x;               // over B * (T/16)
    const int b   = blk / (TLEN / 16);
    const int tc  = blk % (TLEN / 16);
    const int j   = threadIdx.x;
    const int row = (j >> 2) + 128 * (j & 3);

    const float* xsrc = X + ((size_t)b * TLEN + (size_t)tc * 16) * DIN;
    for (int i = j; i < 16 * DIN; i += 512) ((float*)xs)[i] = xsrc[i];
    __syncthreads();

    f4 w[16];
    const f4* wp = (const f4*)(Wih0 + (size_t)row * DIN);
    #pragma unroll
    for (int i = 0; i < 16; ++i) w[i] = wp[i];
    const float bias = bih0[row] + bhh0[row];

    _Float16* dst = XG + ((size_t)b * TLEN + (size_t)tc * 16) * 512 + j;
    #pragma unroll 4
    for (int t = 0; t < 16; ++t) {
        float acc = bias;
        const f4* xv = (const f4*)&xs[t][0];
        #pragma unroll
        for (int i = 0; i < 16; ++i) {
            f4 x4 = xv[i];
            acc += w[i][0] * x4[0] + w[i][1] * x4[1] + w[i][2] * x4[2] + w[i][3] * x4[3];
        }
        dst[(size_t)t * 512] = (_Float16)acc;
    }
}

// ============================================================================
// Kernel 2: 3-stage pipeline. grid = 96: role = bid/32, batch = bid%32.
//  role0: layer0 cell (Whh0 regs) -> H0g stream + F0 flag (chunk 8)
//  role1: xg1 = bias1 + Wih1*h0  -> XG1 ring + F1 flag (chunk 8), C2 backpress
//  role2: layer1 cell (Whh1 regs) <- XG1 prefetch -> Out, C2 every 32
// Each role: 64 weight dwords/thread (fits the observed 128-VGPR hard cap).
// ============================================================================
__global__ __launch_bounds__(512) void lstm2_pipe(
    const _Float16* __restrict__ XG0,
    const float* __restrict__ Whh0,
    const float* __restrict__ Wih1, const float* __restrict__ Whh1,
    const float* __restrict__ bih1, const float* __restrict__ bhh1,
    float* __restrict__ Out,
    u32* __restrict__ H0g,     // [BATCH][TLEN][64] u32 (f16 pairs)
    u32* __restrict__ XG1,     // [BATCH][RING][512] u32 (f32 bits)
    u32* __restrict__ Flags)   // 96 slots x 16 u32 (64B padded)
{
    const int role = blockIdx.x / BATCH;
    const int b    = blockIdx.x % BATCH;
    const int t0   = threadIdx.x;
    const int rg   = t0 >> 2;
    const int kg   = t0 & 3;

    u32* F0 = Flags + (size_t)b * 16;              // h0 produced count
    u32* F1 = Flags + (size_t)(32 + b) * 16;       // xg1 produced count
    u32* C2 = Flags + (size_t)(64 + b) * 16;       // xg1 consumed count

    if (role == 0) {
        // ---------------- layer-0 cell ----------------
        __shared__ alignas(16) _Float16 hl[2][HID];
        u32 w[64];
        load_w_slice(Whh0, rg, kg, w);
        if (t0 < HID) { hl[0][t0] = (_Float16)0.0f; hl[1][t0] = (_Float16)0.0f; }
        float c0 = 0.0f;
        const _Float16* xgp = XG0 + (size_t)b * TLEN * 512 + t0;
        u32* h0out = H0g + (size_t)b * TLEN * 64;
        _Float16 xga = xgp[0];
        _Float16 xgb = xgp[512];
        __syncthreads();

        for (int t = 0; t < TLEN; ++t) {
            const int cur = t & 1, prv = cur ^ 1;
            const float xgv = (float)xga;
            xga = xgb;
            { int tn = (t + 2 < TLEN) ? t + 2 : TLEN - 1; xgb = xgp[(size_t)tn * 512]; }

            float p[4];
            #pragma unroll
            for (int m = 0; m < 4; ++m) p[m] = (kg == m) ? xgv : 0.0f;
            dot_slice(w, (const uint4*)&hl[prv][kg * 32], p);
            qreduce(p);
            float ii = sigm(p[0]), ff = sigm(p[1]);
            float gg = tanh_c(p[2]), oo = sigm(p[3]);
            c0 = ff * c0 + ii * gg;
            if (kg == 0) hl[cur][rg] = (_Float16)(oo * tanh_c(c0));
            __syncthreads();
            // publish h0(t): wave 0 only (64 lanes) -> release fence covers it
            if (t0 < 64)
                astore_rlx(&h0out[(size_t)t * 64 + t0], ((const u32*)hl[cur])[t0]);
            if (t0 == 0 && (t & 7) == 7)
                astore_rel(F0, (u32)(t + 1));   // waits wave0 vmcnt -> orders data
        }
    } else if (role == 1) {
        // ---------------- xg1 producer ----------------
        __shared__ alignas(16) u32 h0s[64];
        __shared__ u32 sa, sc;
        u32 w[64];
        load_w_slice(Wih1, rg, kg, w);
        const int rowk = rg + 128 * kg;
        const float B1 = bih1[rowk] + bhh1[rowk];
        if (t0 == 0) { sa = 0u; sc = 0u; }
        u32* H0in = H0g + (size_t)b * TLEN * 64;
        u32* xout = XG1 + (size_t)b * RING * 512;
        __syncthreads();

        for (int t = 0; t < TLEN; ++t) {
            if (t0 == 0) {
                u32 av = sa;
                if (av < (u32)(t + 1)) {
                    long g = 0;
                    do { av = aload_acq(F0);
                         if (av >= (u32)(t + 1)) break;
                         __builtin_amdgcn_s_sleep(2);
                    } while (++g < 50000000L);
                    sa = av;
                }
                u32 cv = sc;
                if ((u32)t >= cv + (RING - 64)) {
                    long g = 0;
                    do { cv = aload_rlx(C2);
                         if ((u32)t < cv + (RING - 64)) break;
                         __builtin_amdgcn_s_sleep(2);
                    } while (++g < 50000000L);
                    sc = cv;
                }
            }
            __syncthreads();                 // poll result + h0s reuse safe
            if (t0 < 64) h0s[t0] = aload_rlx(&H0in[(size_t)t * 64 + t0]);
            __syncthreads();

            float p[4];
            #pragma unroll
            for (int m = 0; m < 4; ++m) p[m] = (kg == m) ? B1 : 0.0f;
            dot_slice(w, (const uint4*)&h0s[kg * 16], p);
            qreduce(p);
            // element index for (unit rg, gate kg) is exactly t0
            astore_rlx(&xout[(size_t)(t & (RING - 1)) * 512 + t0],
                       __builtin_bit_cast(u32, p[kg]));
            if ((t & 7) == 7) {
                asm volatile("s_waitcnt vmcnt(0)" ::: "memory");
                __syncthreads();             // all waves' stores drained
                if (t0 == 0) astore_rel(F1, (u32)(t + 1));
            }
        }
    } else {
        // ---------------- layer-1 cell ----------------
        __shared__ alignas(16) _Float16 hl[2][HID];
        __shared__ u32 sa;
        u32 w[64];
        load_w_slice(Whh1, rg, kg, w);
        if (t0 < HID) { hl[0][t0] = (_Float16)0.0f; hl[1][t0] = (_Float16)0.0f; }
        if (t0 == 0) sa = 0u;
        u32* xin = XG1 + (size_t)b * RING * 512;
        float c1 = 0.0f;
        float xg_next = 0.0f;
        bool have = false;
        __syncthreads();

        for (int t = 0; t < TLEN; ++t) {
            const int cur = t & 1, prv = cur ^ 1;
            float xgv;
            if (have) {
                xgv = xg_next;
            } else {
                if (t0 == 0) {
                    u32 av = sa;
                    if (av < (u32)(t + 1)) {
                        long g = 0;
                        do { av = aload_acq(F1);
                             if (av >= (u32)(t + 1)) break;
                             __builtin_amdgcn_s_sleep(2);
                        } while (++g < 50000000L);
                        sa = av;
                    }
                }
                __syncthreads();
                xgv = __builtin_bit_cast(float,
                        aload_rlx(&xin[(size_t)(t & (RING - 1)) * 512 + t0]));
            }
            // opportunistic flag refresh (issued early, used after compute)
            u32 avref = 0;
            if (t0 == 0) avref = aload_acq(F1);

            float q[4];
            #pragma unroll
            for (int m = 0; m < 4; ++m) q[m] = (kg == m) ? xgv : 0.0f;
            dot_slice(w, (const uint4*)&hl[prv][kg * 32], q);
            qreduce(q);
            float ii = sigm(q[0]), ff = sigm(q[1]);
            float gg = tanh_c(q[2]), oo = sigm(q[3]);
            c1 = ff * c1 + ii * gg;
            float h1v = oo * tanh_c(c1);
            if (kg == 0) {
                hl[cur][rg] = (_Float16)h1v;
                Out[((size_t)b * TLEN + t) * HID + rg] = h1v;
            }
            if (t0 == 0 && avref > sa) sa = avref;
            __syncthreads();                 // hl + sa published

            have = false;
            if (sa >= (u32)(t + 2)) {        // block-uniform decision
                xg_next = __builtin_bit_cast(float,
                    aload_rlx(&xin[(size_t)((t + 1) & (RING - 1)) * 512 + t0]));
                have = true;
            }
            if (t0 == 0 && (t & 31) == 31) astore_rlx(C2, (u32)(t + 1));
        }
    }
}

// ============================================================================
// Fallback (ws too small): round-1 kernel, known-correct at 6.8 ms.
// ============================================================================
__global__ __launch_bounds__(512, 2) void lstm2_persist(
    const float* __restrict__ X,
    const float* __restrict__ Wih0, const float* __restrict__ Whh0,
    const float* __restrict__ bih0, const float* __restrict__ bhh0,
    const float* __restrict__ Wih1, const float* __restrict__ Whh1,
    const float* __restrict__ bih1, const float* __restrict__ bhh1,
    float* __restrict__ Out)
{
    __shared__ unsigned int wih0_lds[512 * 33];
    __shared__ _Float16 h0buf[2][HID];
    __shared__ _Float16 h1buf[2][HID];

    const int b  = blockIdx.x;
    const int t  = threadIdx.x;
    const int rg = t >> 2;
    const int kg = t & 3;

    {
        const float2* src = (const float2*)(Wih0 + t * DIN);
        #pragma unroll
        for (int i = 0; i < 32; ++i) {
            float2 v = src[i];
            h2 p; p.x = (_Float16)v.x; p.y = (_Float16)v.y;
            wih0_lds[t * 33 + i] = __builtin_bit_cast(unsigned int, p);
        }
    }
    if (t < HID) {
        h0buf[0][t] = (_Float16)0.0f; h0buf[1][t] = (_Float16)0.0f;
        h1buf[0][t] = (_Float16)0.0f; h1buf[1][t] = (_Float16)0.0f;
    }

    h2 whh0[4][16], wih1[4][16], whh1[4][16];
    float bi0[4], bi1[4];
    #pragma unroll
    for (int m = 0; m < 4; ++m) {
        const int row = rg + 128 * m;
        const float2* a = (const float2*)(Whh0 + row * HID + kg * 32);
        const float2* c = (const float2*)(Wih1 + row * HID + kg * 32);
        const float2* d = (const float2*)(Whh1 + row * HID + kg * 32);
        #pragma unroll
        for (int i = 0; i < 16; ++i) {
            float2 v; h2 w;
            v = a[i]; w.x = (_Float16)v.x; w.y = (_Float16)v.y; whh0[m][i] = w;
            v = c[i]; w.x = (_Float16)v.x; w.y = (_Float16)v.y; wih1[m][i] = w;
            v = d[i]; w.x = (_Float16)v.x; w.y = (_Float16)v.y; whh1[m][i] = w;
        }
        bi0[m] = (kg == 0) ? (bih0[row] + bhh0[row]) : 0.0f;
        bi1[m] = (kg == 0) ? (bih1[row] + bhh1[row]) : 0.0f;
    }

    float c0 = 0.0f, c1 = 0.0f;
    __syncthreads();

    f4 xA[4], xB[4];
    {
        const f4* xp = (const f4*)(X + ((size_t)b * TLEN) * DIN + kg * 16);
        #pragma unroll
        for (int j = 0; j < 4; ++j) xA[j] = xp[j];
    }

    auto step = [&](int tt, f4 (&xc)[4], f4 (&xn)[4]) {
        const int cur = tt & 1, nxt = cur ^ 1;
        h2 xh[8];
        const float* xf = (const float*)xc;
        #pragma unroll
        for (int j = 0; j < 8; ++j) {
            h2 p; p.x = (_Float16)xf[2 * j]; p.y = (_Float16)xf[2 * j + 1];
            xh[j] = p;
        }
        {
            const int tn = (tt + 1 < TLEN) ? tt + 1 : TLEN - 1;
            const f4* xp = (const f4*)(X + ((size_t)b * TLEN + tn) * DIN + kg * 16);
            #pragma unroll
            for (int j = 0; j < 4; ++j) xn[j] = xp[j];
        }
        float p0[4];
        #pragma unroll
        for (int m = 0; m < 4; ++m) p0[m] = bi0[m];
        #pragma unroll
        for (int m = 0; m < 4; ++m) {
            const unsigned int* wr = &wih0_lds[(rg + 128 * m) * 33 + kg * 8];
            #pragma unroll
            for (int i = 0; i < 8; ++i) {
                h2 w = __builtin_bit_cast(h2, wr[i]);
                p0[m] = FDOT2(w, xh[i], p0[m]);
            }
        }
        {
            const unsigned int* hr = (const unsigned int*)&h0buf[cur][0];
            #pragma unroll
            for (int i = 0; i < 16; ++i) {
                h2 hv = __builtin_bit_cast(h2, hr[kg * 16 + i]);
                #pragma unroll
                for (int m = 0; m < 4; ++m)
                    p0[m] = FDOT2(whh0[m][i], hv, p0[m]);
            }
        }
        #pragma unroll
        for (int m = 0; m < 4; ++m) {
            p0[m] += __shfl_xor(p0[m], 1, 4);
            p0[m] += __shfl_xor(p0[m], 2, 4);
        }
        {
            float ii = sigm(p0[0]), ff = sigm(p0[1]);
            float gg = tanh_c(p0[2]), oo = sigm(p0[3]);
            c0 = ff * c0 + ii * gg;
            float h0v = oo * tanh_c(c0);
            if (kg == 0) h0buf[nxt][rg] = (_Float16)h0v;
        }
        __syncthreads();
        float q[4];
        #pragma unroll
        for (int m = 0; m < 4; ++m) q[m] = bi1[m];
        {
            const unsigned int* hr = (const unsigned int*)&h0buf[nxt][0];
            #pragma unroll
            for (int i = 0; i < 16; ++i) {
                h2 hv = __builtin_bit_cast(h2, hr[kg * 16 + i]);
                #pragma unroll
                for (int m = 0; m < 4; ++m)
                    q[m] = FDOT2(wih1[m][i], hv, q[m]);
            }
        }
        {
            const unsigned int* hr = (const unsigned int*)&h1buf[cur][0];
            #pragma unroll
            for (int i = 0; i < 16; ++i) {
                h2 hv = __builtin_bit_cast(h2, hr[kg * 16 + i]);
                #pragma unroll
                for (int m = 0; m < 4; ++m)
                    q[m] = FDOT2(whh1[m][i], hv, q[m]);
            }
        }
        #pragma unroll
        for (int m = 0; m < 4; ++m) {
            q[m] += __shfl_xor(q[m], 1, 4);
            q[m] += __shfl_xor(q[m], 2, 4);
        }
        {
            float ii = sigm(q[0]), ff = sigm(q[1]);
            float gg = tanh_c(q[2]), oo = sigm(q[3]);
            c1 = ff * c1 + ii * gg;
            float h1v = oo * tanh_c(c1);
            if (kg == 0) {
                h1buf[nxt][rg] = (_Float16)h1v;
                Out[((size_t)b * TLEN + tt) * HID + rg] = h1v;
            }
        }
        __syncthreads();
    };

    for (int tt = 0; tt < TLEN; tt += 2) {
        step(tt, xA, xB);
        step(tt + 1, xB, xA);
    }
}

extern "C" void kernel_launch(void* const* d_in, const int* in_sizes, int n_in,
                              void* d_out, int out_size, void* d_ws, size_t ws_size,
                              hipStream_t stream) {
    const float* X    = (const float*)d_in[0];
    const float* Wih0 = (const float*)d_in[1];
    const float* Whh0 = (const float*)d_in[2];
    const float* bih0 = (const float*)d_in[3];
    const float* bhh0 = (const float*)d_in[4];
    const float* Wih1 = (const float*)d_in[5];
    const float* Whh1 = (const float*)d_in[6];
    const float* bih1 = (const float*)d_in[7];
    const float* bhh1 = (const float*)d_in[8];
    float* Out = (float*)d_out;

    // ws layout
    const size_t XG0_B  = (size_t)BATCH * TLEN * 512 * 2;   // 64 MiB f16
    const size_t H0_B   = (size_t)BATCH * TLEN * 64 * 4;    // 16 MiB
    const size_t XG1_B  = (size_t)BATCH * RING * 512 * 4;   // 16 MiB
    const size_t FLAG_B = 96 * 16 * 4;                      // 6 KiB
    const size_t NEED   = XG0_B + H0_B + XG1_B + FLAG_B;

    if (ws_size >= NEED) {
        char* ws = (char*)d_ws;
        _Float16* XG0 = (_Float16*)ws;
        u32* H0g   = (u32*)(ws + XG0_B);
        u32* XG1   = (u32*)(ws + XG0_B + H0_B);
        u32* Flags = (u32*)(ws + XG0_B + H0_B + XG1_B);

        hipMemsetAsync(Flags, 0, FLAG_B, stream);   // re-arm sync every launch
        xg_precompute<<<dim3(BATCH * (TLEN / 16)), dim3(512), 0, stream>>>(
            X, Wih0, bih0, bhh0, XG0);
        lstm2_pipe<<<dim3(3 * BATCH), dim3(512), 0, stream>>>(
            XG0, Whh0, Wih1, Whh1, bih1, bhh1, Out, H0g, XG1, Flags);
    } else {
        lstm2_persist<<<dim3(BATCH), dim3(512), 0, stream>>>(
            X, Wih0, Whh0, bih0, bhh0, Wih1, Whh1, bih1, bhh1, Out);
    }
}

// Round 9
// 2338.303 us; speedup vs baseline: 2.0308x; 1.0900x over previous
//
#include <hip/hip_runtime.h>

#define TLEN 2048
#define BATCH 32
#define DIN 64
#define HID 128
#define RING 256   // xg1 ring depth (steps); power of 2, multiple of CHK
#define CHK 8      // pipeline chunk (steps); flag/prefetch granularity

typedef _Float16 h2 __attribute__((ext_vector_type(2)));
typedef float f4 __attribute__((ext_vector_type(4)));
typedef unsigned int u32;

#if defined(__has_builtin)
#if __has_builtin(__builtin_amdgcn_fdot2)
#define FDOT2(a, b, c) __builtin_amdgcn_fdot2((a), (b), (c), false)
#endif
#endif
#ifndef FDOT2
#define FDOT2(a, b, c) ((c) + (float)(a).x * (float)(b).x + (float)(a).y * (float)(b).y)
#endif
#define DOT2U(wu, hv, acc) FDOT2(__builtin_bit_cast(h2, (wu)), (hv), (acc))

__device__ __forceinline__ float sigm(float x) { return 1.0f / (1.0f + __expf(-x)); }
__device__ __forceinline__ float tanh_c(float x) {
    x = fminf(fmaxf(x, -15.0f), 15.0f);
    float e = __expf(2.0f * x);
    return (e - 1.0f) / (e + 1.0f);
}
__device__ __forceinline__ void qreduce(float (&v)[4]) {
    #pragma unroll
    for (int m = 0; m < 4; ++m) {
        v[m] += __shfl_xor(v[m], 1, 4);
        v[m] += __shfl_xor(v[m], 2, 4);
    }
}

// agent-scope atomics: the cross-XCD-coherent path (R8-proven)
__device__ __forceinline__ u32 aload_rlx(u32* p) {
    return __hip_atomic_load(p, __ATOMIC_RELAXED, __HIP_MEMORY_SCOPE_AGENT);
}
__device__ __forceinline__ u32 aload_acq(u32* p) {
    return __hip_atomic_load(p, __ATOMIC_ACQUIRE, __HIP_MEMORY_SCOPE_AGENT);
}
__device__ __forceinline__ void astore_rlx(u32* p, u32 v) {
    __hip_atomic_store(p, v, __ATOMIC_RELAXED, __HIP_MEMORY_SCOPE_AGENT);
}
__device__ __forceinline__ void astore_rel(u32* p, u32 v) {
    __hip_atomic_store(p, v, __ATOMIC_RELEASE, __HIP_MEMORY_SCOPE_AGENT);
}

// f16-pair weight slice for gate rows {rg+128m}, k-slice [kg*32, kg*32+32)
__device__ __forceinline__ void load_w_slice(const float* __restrict__ W,
                                             int rg, int kg, u32 (&w)[64]) {
    #pragma unroll
    for (int m = 0; m < 4; ++m) {
        const float2* a = (const float2*)(W + (size_t)(rg + 128 * m) * HID + kg * 32);
        #pragma unroll
        for (int i = 0; i < 16; ++i) {
            float2 v = a[i];
            h2 x; x.x = (_Float16)v.x; x.y = (_Float16)v.y;
            w[m * 16 + i] = __builtin_bit_cast(u32, x);
        }
    }
    // one-time residency pins: block remat/sinking of the loop-invariant
    // weight loads into the time loop (the R8 VGPR=68 failure mode).
    #pragma unroll
    for (int i = 0; i < 64; ++i) asm volatile("" : "+v"(w[i]));
}
// 64 dot2 over a 32-elem f16 h-slice (LDS), accumulating 4 gate partials
__device__ __forceinline__ void dot_slice(const u32 (&w)[64],
                                          const uint4* __restrict__ H,
                                          float (&p)[4]) {
    #pragma unroll
    for (int qr = 0; qr < 4; ++qr) {
        u32 hw[4];
        *(uint4*)hw = H[qr];
        #pragma unroll
        for (int ww = 0; ww < 4; ++ww) {
            const h2 hv = __builtin_bit_cast(h2, hw[ww]);
            #pragma unroll
            for (int m = 0; m < 4; ++m)
                p[m] = DOT2U(w[m * 16 + qr * 4 + ww], hv, p[m]);
        }
    }
}

// ============================================================================
// Kernel 1: XG0[b,t,j] = Wih0[row_j]·x[b,t] + bih0[row_j] + bhh0[row_j], f16.
// row_j = (j>>2) + 128*(j&3); layout matches pipeline thread mapping.
// ============================================================================
__global__ __launch_bounds__(512) void xg_precompute(
    const float* __restrict__ X, const float* __restrict__ Wih0,
    const float* __restrict__ bih0, const float* __restrict__ bhh0,
    _Float16* __restrict__ XG)
{
    __shared__ float xs[16][DIN];
    const int blk = blockIdx.x;               // over B * (T/16)
    const int b   = blk / (TLEN / 16);
    const int tc  = blk % (TLEN / 16);
    const int j   = threadIdx.x;
    const int row = (j >> 2) + 128 * (j & 3);

    const float* xsrc = X + ((size_t)b * TLEN + (size_t)tc * 16) * DIN;
    for (int i = j; i < 16 * DIN; i += 512) ((float*)xs)[i] = xsrc[i];
    __syncthreads();

    f4 w[16];
    const f4* wp = (const f4*)(Wih0 + (size_t)row * DIN);
    #pragma unroll
    for (int i = 0; i < 16; ++i) w[i] = wp[i];
    const float bias = bih0[row] + bhh0[row];

    _Float16* dst = XG + ((size_t)b * TLEN + (size_t)tc * 16) * 512 + j;
    #pragma unroll 4
    for (int t = 0; t < 16; ++t) {
        float acc = bias;
        const f4* xv = (const f4*)&xs[t][0];
        #pragma unroll
        for (int i = 0; i < 16; ++i) {
            f4 x4 = xv[i];
            acc += w[i][0] * x4[0] + w[i][1] * x4[1] + w[i][2] * x4[2] + w[i][3] * x4[3];
        }
        dst[(size_t)t * 512] = (_Float16)acc;
    }
}

// ============================================================================
// Kernel 2: 3-stage pipeline, grid = 96: role = bid/32, batch = bid%32.
//  role0: layer0 cell (Whh0 regs)  -> H0g stream, F0 release every CHK
//  role1: xg1 = bias1 + Wih1*h0    -> XG1 ring,  F1 release every CHK;
//         h0 prefetched a CHUNK at a time into LDS (one latency / 8 steps)
//  role2: layer1 cell (Whh1 regs)  <- xg1 prefetched a CHUNK at a time -> Out
// __launch_bounds__(512,2): explicit min-blocks selects the 128-VGPR budget
// (R1/R3/R5 evidence); 64-dw weights + ~30 working fit -> truly resident.
// ============================================================================
__global__ __launch_bounds__(512, 2) void lstm2_pipe(
    const _Float16* __restrict__ XG0,
    const float* __restrict__ Whh0,
    const float* __restrict__ Wih1, const float* __restrict__ Whh1,
    const float* __restrict__ bih1, const float* __restrict__ bhh1,
    float* __restrict__ Out,
    u32* __restrict__ H0g,     // [BATCH][TLEN][64] u32 (f16 pairs)
    u32* __restrict__ XG1,     // [BATCH][RING][512] u32 (f32 bits)
    u32* __restrict__ Flags)   // 96 slots x 16 u32 (64B padded)
{
    const int role = blockIdx.x / BATCH;
    const int b    = blockIdx.x % BATCH;
    const int t0   = threadIdx.x;
    const int rg   = t0 >> 2;
    const int kg   = t0 & 3;

    u32* F0 = Flags + (size_t)b * 16;              // h0 produced count
    u32* F1 = Flags + (size_t)(32 + b) * 16;       // xg1 produced count
    u32* C2 = Flags + (size_t)(64 + b) * 16;       // xg1 consumed count

    if (role == 0) {
        // ---------------- layer-0 cell (R8-proven) ----------------
        __shared__ alignas(16) _Float16 hl[2][HID];
        u32 w[64];
        load_w_slice(Whh0, rg, kg, w);
        if (t0 < HID) { hl[0][t0] = (_Float16)0.0f; hl[1][t0] = (_Float16)0.0f; }
        float c0 = 0.0f;
        const _Float16* xgp = XG0 + (size_t)b * TLEN * 512 + t0;
        u32* h0out = H0g + (size_t)b * TLEN * 64;
        _Float16 xga = xgp[0];
        _Float16 xgb = xgp[512];
        __syncthreads();

        for (int t = 0; t < TLEN; ++t) {
            const int cur = t & 1, prv = cur ^ 1;
            const float xgv = (float)xga;
            xga = xgb;
            { int tn = (t + 2 < TLEN) ? t + 2 : TLEN - 1; xgb = xgp[(size_t)tn * 512]; }

            float p[4];
            #pragma unroll
            for (int m = 0; m < 4; ++m) p[m] = (kg == m) ? xgv : 0.0f;
            dot_slice(w, (const uint4*)&hl[prv][kg * 32], p);
            qreduce(p);
            float ii = sigm(p[0]), ff = sigm(p[1]);
            float gg = tanh_c(p[2]), oo = sigm(p[3]);
            c0 = ff * c0 + ii * gg;
            if (kg == 0) hl[cur][rg] = (_Float16)(oo * tanh_c(c0));
            __syncthreads();
            // publish h0(t): wave 0 only -> t0==0's release drains wave0 stores
            if (t0 < 64)
                astore_rlx(&h0out[(size_t)t * 64 + t0], ((const u32*)hl[cur])[t0]);
            if (t0 == 0 && (t & (CHK - 1)) == (CHK - 1))
                astore_rel(F0, (u32)(t + 1));
        }
    } else if (role == 1) {
        // ---------------- xg1 producer, chunk-prefetched ----------------
        __shared__ alignas(16) u32 h0c[CHK * 64];   // one chunk of h0
        u32 w[64];
        load_w_slice(Wih1, rg, kg, w);
        const int rowk = rg + 128 * kg;
        const float B1 = bih1[rowk] + bhh1[rowk];
        u32* H0in = H0g + (size_t)b * TLEN * 64;
        u32* xout = XG1 + (size_t)b * RING * 512;
        u32 sc = 0;   // cached C2 (uniform, t0==0 only)
        __syncthreads();

        for (int c = 0; c < TLEN / CHK; ++c) {
            const int tbase = c * CHK;
            if (t0 == 0) {
                u32 av; long g = 0;
                do { av = aload_acq(F0);
                     if (av >= (u32)(tbase + CHK)) break;
                     __builtin_amdgcn_s_sleep(2);
                } while (++g < 50000000L);
                if (tbase + CHK > (int)sc + (RING - 64)) {     // backpressure
                    g = 0;
                    do { sc = aload_rlx(C2);
                         if (tbase + CHK <= (int)sc + (RING - 64)) break;
                         __builtin_amdgcn_s_sleep(2);
                    } while (++g < 50000000L);
                }
            }
            __syncthreads();                        // poll done; h0c reusable
            h0c[t0] = aload_rlx(&H0in[(size_t)tbase * 64 + t0]);  // 512 = CHK*64
            __syncthreads();

            #pragma unroll
            for (int s = 0; s < CHK; ++s) {
                const int t = tbase + s;
                float p[4];
                #pragma unroll
                for (int m = 0; m < 4; ++m) p[m] = (kg == m) ? B1 : 0.0f;
                dot_slice(w, (const uint4*)&h0c[s * 64 + kg * 16], p);
                qreduce(p);
                astore_rlx(&xout[(size_t)((t & (RING - 1))) * 512 + t0],
                           __builtin_bit_cast(u32, p[kg]));
            }
            asm volatile("s_waitcnt vmcnt(0)" ::: "memory");   // drain all waves
            __syncthreads();
            if (t0 == 0) astore_rel(F1, (u32)(tbase + CHK));
        }
    } else {
        // ---------------- layer-1 cell, chunk-prefetched ----------------
        __shared__ alignas(16) _Float16 hl[2][HID];
        __shared__ alignas(16) u32 xgc[CHK * 512];  // one chunk of xg1 (16 KB)
        u32 w[64];
        load_w_slice(Whh1, rg, kg, w);
        if (t0 < HID) { hl[0][t0] = (_Float16)0.0f; hl[1][t0] = (_Float16)0.0f; }
        u32* xin = XG1 + (size_t)b * RING * 512;
        float c1 = 0.0f;
        __syncthreads();

        for (int c = 0; c < TLEN / CHK; ++c) {
            const int tbase = c * CHK;
            if (t0 == 0) {
                u32 av; long g = 0;
                do { av = aload_acq(F1);
                     if (av >= (u32)(tbase + CHK)) break;
                     __builtin_amdgcn_s_sleep(2);
                } while (++g < 50000000L);
            }
            __syncthreads();
            const size_t rbase = (size_t)(tbase & (RING - 1)) * 512;  // CHK|RING
            #pragma unroll
            for (int k = 0; k < CHK; ++k)
                xgc[k * 512 + t0] = aload_rlx(&xin[rbase + k * 512 + t0]);
            __syncthreads();

            #pragma unroll 1
            for (int s = 0; s < CHK; ++s) {
                const int t = tbase + s;
                const int cur = t & 1, prv = cur ^ 1;
                const float xgv = __builtin_bit_cast(float, xgc[s * 512 + t0]);

                float q[4];
                #pragma unroll
                for (int m = 0; m < 4; ++m) q[m] = (kg == m) ? xgv : 0.0f;
                dot_slice(w, (const uint4*)&hl[prv][kg * 32], q);
                qreduce(q);
                float ii = sigm(q[0]), ff = sigm(q[1]);
                float gg = tanh_c(q[2]), oo = sigm(q[3]);
                c1 = ff * c1 + ii * gg;
                float h1v = oo * tanh_c(c1);
                if (kg == 0) {
                    hl[cur][rg] = (_Float16)h1v;
                    Out[((size_t)b * TLEN + t) * HID + rg] = h1v;
                }
                __syncthreads();
            }
            if (t0 == 0 && (c & 3) == 3)            // consumption, every 32 steps
                astore_rlx(C2, (u32)(tbase + CHK));
        }
    }
}

// ============================================================================
// Fallback (ws too small): round-1 kernel, known-correct at 6.8 ms.
// ============================================================================
__global__ __launch_bounds__(512, 2) void lstm2_persist(
    const float* __restrict__ X,
    const float* __restrict__ Wih0, const float* __restrict__ Whh0,
    const float* __restrict__ bih0, const float* __restrict__ bhh0,
    const float* __restrict__ Wih1, const float* __restrict__ Whh1,
    const float* __restrict__ bih1, const float* __restrict__ bhh1,
    float* __restrict__ Out)
{
    __shared__ unsigned int wih0_lds[512 * 33];
    __shared__ _Float16 h0buf[2][HID];
    __shared__ _Float16 h1buf[2][HID];

    const int b  = blockIdx.x;
    const int t  = threadIdx.x;
    const int rg = t >> 2;
    const int kg = t & 3;

    {
        const float2* src = (const float2*)(Wih0 + t * DIN);
        #pragma unroll
        for (int i = 0; i < 32; ++i) {
            float2 v = src[i];
            h2 p; p.x = (_Float16)v.x; p.y = (_Float16)v.y;
            wih0_lds[t * 33 + i] = __builtin_bit_cast(unsigned int, p);
        }
    }
    if (t < HID) {
        h0buf[0][t] = (_Float16)0.0f; h0buf[1][t] = (_Float16)0.0f;
        h1buf[0][t] = (_Float16)0.0f; h1buf[1][t] = (_Float16)0.0f;
    }

    h2 whh0[4][16], wih1[4][16], whh1[4][16];
    float bi0[4], bi1[4];
    #pragma unroll
    for (int m = 0; m < 4; ++m) {
        const int row = rg + 128 * m;
        const float2* a = (const float2*)(Whh0 + row * HID + kg * 32);
        const float2* c = (const float2*)(Wih1 + row * HID + kg * 32);
        const float2* d = (const float2*)(Whh1 + row * HID + kg * 32);
        #pragma unroll
        for (int i = 0; i < 16; ++i) {
            float2 v; h2 w;
            v = a[i]; w.x = (_Float16)v.x; w.y = (_Float16)v.y; whh0[m][i] = w;
            v = c[i]; w.x = (_Float16)v.x; w.y = (_Float16)v.y; wih1[m][i] = w;
            v = d[i]; w.x = (_Float16)v.x; w.y = (_Float16)v.y; whh1[m][i] = w;
        }
        bi0[m] = (kg == 0) ? (bih0[row] + bhh0[row]) : 0.0f;
        bi1[m] = (kg == 0) ? (bih1[row] + bhh1[row]) : 0.0f;
    }

    float c0 = 0.0f, c1 = 0.0f;
    __syncthreads();

    f4 xA[4], xB[4];
    {
        const f4* xp = (const f4*)(X + ((size_t)b * TLEN) * DIN + kg * 16);
        #pragma unroll
        for (int j = 0; j < 4; ++j) xA[j] = xp[j];
    }

    auto step = [&](int tt, f4 (&xc)[4], f4 (&xn)[4]) {
        const int cur = tt & 1, nxt = cur ^ 1;
        h2 xh[8];
        const float* xf = (const float*)xc;
        #pragma unroll
        for (int j = 0; j < 8; ++j) {
            h2 p; p.x = (_Float16)xf[2 * j]; p.y = (_Float16)xf[2 * j + 1];
            xh[j] = p;
        }
        {
            const int tn = (tt + 1 < TLEN) ? tt + 1 : TLEN - 1;
            const f4* xp = (const f4*)(X + ((size_t)b * TLEN + tn) * DIN + kg * 16);
            #pragma unroll
            for (int j = 0; j < 4; ++j) xn[j] = xp[j];
        }
        float p0[4];
        #pragma unroll
        for (int m = 0; m < 4; ++m) p0[m] = bi0[m];
        #pragma unroll
        for (int m = 0; m < 4; ++m) {
            const unsigned int* wr = &wih0_lds[(rg + 128 * m) * 33 + kg * 8];
            #pragma unroll
            for (int i = 0; i < 8; ++i) {
                h2 w = __builtin_bit_cast(h2, wr[i]);
                p0[m] = FDOT2(w, xh[i], p0[m]);
            }
        }
        {
            const unsigned int* hr = (const unsigned int*)&h0buf[cur][0];
            #pragma unroll
            for (int i = 0; i < 16; ++i) {
                h2 hv = __builtin_bit_cast(h2, hr[kg * 16 + i]);
                #pragma unroll
                for (int m = 0; m < 4; ++m)
                    p0[m] = FDOT2(whh0[m][i], hv, p0[m]);
            }
        }
        #pragma unroll
        for (int m = 0; m < 4; ++m) {
            p0[m] += __shfl_xor(p0[m], 1, 4);
            p0[m] += __shfl_xor(p0[m], 2, 4);
        }
        {
            float ii = sigm(p0[0]), ff = sigm(p0[1]);
            float gg = tanh_c(p0[2]), oo = sigm(p0[3]);
            c0 = ff * c0 + ii * gg;
            float h0v = oo * tanh_c(c0);
            if (kg == 0) h0buf[nxt][rg] = (_Float16)h0v;
        }
        __syncthreads();
        float q[4];
        #pragma unroll
        for (int m = 0; m < 4; ++m) q[m] = bi1[m];
        {
            const unsigned int* hr = (const unsigned int*)&h0buf[nxt][0];
            #pragma unroll
            for (int i = 0; i < 16; ++i) {
                h2 hv = __builtin_bit_cast(h2, hr[kg * 16 + i]);
                #pragma unroll
                for (int m = 0; m < 4; ++m)
                    q[m] = FDOT2(wih1[m][i], hv, q[m]);
            }
        }
        {
            const unsigned int* hr = (const unsigned int*)&h1buf[cur][0];
            #pragma unroll
            for (int i = 0; i < 16; ++i) {
                h2 hv = __builtin_bit_cast(h2, hr[kg * 16 + i]);
                #pragma unroll
                for (int m = 0; m < 4; ++m)
                    q[m] = FDOT2(whh1[m][i], hv, q[m]);
            }
        }
        #pragma unroll
        for (int m = 0; m < 4; ++m) {
            q[m] += __shfl_xor(q[m], 1, 4);
            q[m] += __shfl_xor(q[m], 2, 4);
        }
        {
            float ii = sigm(q[0]), ff = sigm(q[1]);
            float gg = tanh_c(q[2]), oo = sigm(q[3]);
            c1 = ff * c1 + ii * gg;
            float h1v = oo * tanh_c(c1);
            if (kg == 0) {
                h1buf[nxt][rg] = (_Float16)h1v;
                Out[((size_t)b * TLEN + tt) * HID + rg] = h1v;
            }
        }
        __syncthreads();
    };

    for (int tt = 0; tt < TLEN; tt += 2) {
        step(tt, xA, xB);
        step(tt + 1, xB, xA);
    }
}

extern "C" void kernel_launch(void* const* d_in, const int* in_sizes, int n_in,
                              void* d_out, int out_size, void* d_ws, size_t ws_size,
                              hipStream_t stream) {
    const float* X    = (const float*)d_in[0];
    const float* Wih0 = (const float*)d_in[1];
    const float* Whh0 = (const float*)d_in[2];
    const float* bih0 = (const float*)d_in[3];
    const float* bhh0 = (const float*)d_in[4];
    const float* Wih1 = (const float*)d_in[5];
    const float* Whh1 = (const float*)d_in[6];
    const float* bih1 = (const float*)d_in[7];
    const float* bhh1 = (const float*)d_in[8];
    float* Out = (float*)d_out;

    // ws layout
    const size_t XG0_B  = (size_t)BATCH * TLEN * 512 * 2;   // 64 MiB f16
    const size_t H0_B   = (size_t)BATCH * TLEN * 64 * 4;    // 16 MiB
    const size_t XG1_B  = (size_t)BATCH * RING * 512 * 4;   // 16 MiB
    const size_t FLAG_B = 96 * 16 * 4;                      // 6 KiB
    const size_t NEED   = XG0_B + H0_B + XG1_B + FLAG_B;

    if (ws_size >= NEED) {
        char* ws = (char*)d_ws;
        _Float16* XG0 = (_Float16*)ws;
        u32* H0g   = (u32*)(ws + XG0_B);
        u32* XG1   = (u32*)(ws + XG0_B + H0_B);
        u32* Flags = (u32*)(ws + XG0_B + H0_B + XG1_B);

        hipMemsetAsync(Flags, 0, FLAG_B, stream);   // re-arm sync every launch
        xg_precompute<<<dim3(BATCH * (TLEN / 16)), dim3(512), 0, stream>>>(
            X, Wih0, bih0, bhh0, XG0);
        lstm2_pipe<<<dim3(3 * BATCH), dim3(512), 0, stream>>>(
            XG0, Whh0, Wih1, Whh1, bih1, bhh1, Out, H0g, XG1, Flags);
    } else {
        lstm2_persist<<<dim3(BATCH), dim3(512), 0, stream>>>(
            X, Wih0, Whh0, bih0, bhh0, Wih1, Whh1, bih1, bhh1, Out);
    }
}